// Round 20
// baseline (394.492 us; speedup 1.0000x reference)
//
#include <hip/hip_runtime.h>

typedef __attribute__((ext_vector_type(8))) short bfrag;   // 8 x bf16
typedef __attribute__((ext_vector_type(4))) float ffrag;   // 4 x f32

struct alignas(16) U8v { unsigned int u[4]; };

__device__ __forceinline__ unsigned int cvt_pk_bf16(float lo, float hi) {
    unsigned int r;
    asm("v_cvt_pk_bf16_f32 %0, %1, %2" : "=v"(r) : "v"(lo), "v"(hi));
    return r;
}
__device__ __forceinline__ unsigned short f2bf1(float x) {
    return (unsigned short)cvt_pk_bf16(x, x);
}

// ---- prep: transpose + bf16-convert weights (r2-proven) ----
__global__ void prep_kernel(const float* __restrict__ Wlin,
                            const float* __restrict__ W1,
                            const float* __restrict__ W2,
                            unsigned short* __restrict__ wlinT,
                            unsigned short* __restrict__ w1T,
                            unsigned short* __restrict__ w2T) {
    int idx = blockIdx.x * 256 + threadIdx.x;           // 0..32767
    { int e = idx >> 7, h = idx & 127; wlinT[h * 256 + e] = f2bf1(Wlin[idx]); }
    if (idx < 16384) {
        int h = idx >> 7, f = idx & 127;
        w1T[f * 128 + h] = f2bf1(W1[idx]);
        w2T[f * 128 + h] = f2bf1(W2[idx]);
    }
}

// ---- fused kernel: 1 block = 2 nodes = 64 rows, 512 thr / 8 waves.
// Tests the last unexplored cell: 3 RESIDENT BLOCKS/CU. LDS 37.6KB via
// single hn/g buffer overlaid into the dead ef region (r17's overlay,
// functionally verified); accum peak h[4]+a2[4]=32 regs -> ~72 live fits
// (512,6)'s 85-reg budget (r17 spilled at 64 accum; this is half).
// 24 waves/CU vs the 16-wave cap of every r7/r16/r18 config.
__global__ __launch_bounds__(512, 6) void fused_kernel(
    const float* __restrict__ ef, const int* __restrict__ mask,
    const unsigned short* __restrict__ wlinT,
    const unsigned short* __restrict__ w1T,
    const unsigned short* __restrict__ w2T,
    const float* __restrict__ b_lin, const float* __restrict__ g_edge,
    const float* __restrict__ b_edge, const float* __restrict__ b1,
    const float* __restrict__ b2, const float* __restrict__ g_node,
    const float* __restrict__ b_node,
    float* __restrict__ out_node, float* __restrict__ out_edge) {

    // phase1-2: ef bf16 [64 rows x 512B, swizzled] @0..32768
    // phase4+:  s_hg bf16 [64 rows x 256B, swizzled] @0..16384 (ef dead)
    __shared__ char  smem[32768];
    __shared__ float s_part[1024];  // 8 waves x 64 rows x {sum,sq}
    __shared__ float s_stat[128];   // [0:64) mu, [64:128) rstd
    __shared__ float s_mask[64];

    float* s_nv = s_part;           // overlay: s_part dead before s_nv written

    const int tid = threadIdx.x;
    const int w = tid >> 6, l = tid & 63, q = l >> 4, c = l & 15;
    const int col = 16 * w + c;
    const int rb = blockIdx.x * 64;                  // 640000/64 = 10000 exact
    const float* efb = ef + (size_t)rb * 256;

    if (tid < 64) s_mask[tid] = (mask[(size_t)rb + tid] != 0) ? 1.f : 0.f;

    // ---- phase 1: stage 64 rows of ef -> bf16 LDS (swizzled 16B slots) ----
    #pragma unroll
    for (int i = 0; i < 4; ++i) {
        int s = i * 512 + tid;          // 2048 slots (64 rows x 32)
        int row = s >> 5, cs = s & 31;
        const float4* p = (const float4*)(efb + (size_t)s * 8);
        float4 v0 = p[0], v1 = p[1];
        U8v u;
        u.u[0] = cvt_pk_bf16(v0.x, v0.y); u.u[1] = cvt_pk_bf16(v0.z, v0.w);
        u.u[2] = cvt_pk_bf16(v1.x, v1.y); u.u[3] = cvt_pk_bf16(v1.z, v1.w);
        *(U8v*)(smem + row * 512 + ((cs * 16) ^ ((row & 7) << 4))) = u;
    }
    __syncthreads();                                   // bar0

    // ---- phase 2: h = ef @ Wlin + b_lin (M=64, K=256, wave's 16 cols) ----
    ffrag h[4] = {};
    #pragma unroll
    for (int kk = 0; kk < 8; ++kk) {
        bfrag bw = *(const bfrag*)(wlinT + col * 256 + kk * 32 + 8 * q);
        #pragma unroll
        for (int mt = 0; mt < 4; ++mt) {
            int row = 16 * mt + c;
            bfrag a = *(const bfrag*)(smem + row * 512 + ((kk * 64 + q * 16) ^ ((row & 7) << 4)));
            h[mt] = __builtin_amdgcn_mfma_f32_16x16x32_bf16(a, bw, h[mt], 0, 0, 0);
        }
    }
    {
        float blc = b_lin[col];
        #pragma unroll
        for (int mt = 0; mt < 4; ++mt)
            #pragma unroll
            for (int r = 0; r < 4; ++r) h[mt][r] += blc;
    }

    // ---- phase 3: edge-LN stats -> dedicated s_part ----
    #pragma unroll
    for (int mt = 0; mt < 4; ++mt)
        #pragma unroll
        for (int r = 0; r < 4; ++r) {
            float s = h[mt][r], qv = h[mt][r] * h[mt][r];
            #pragma unroll
            for (int d = 1; d < 16; d <<= 1) { s += __shfl_xor(s, d); qv += __shfl_xor(qv, d); }
            if (c == 0) {
                int row = 16 * mt + 4 * q + r;
                s_part[w * 128 + row * 2]     = s;
                s_part[w * 128 + row * 2 + 1] = qv;
            }
        }
    __syncthreads();                                   // bar1 (all ef reads done)
    if (tid < 64) {
        float s = 0.f, qv = 0.f;
        #pragma unroll
        for (int ww = 0; ww < 8; ++ww) { s += s_part[ww * 128 + tid * 2]; qv += s_part[ww * 128 + tid * 2 + 1]; }
        float mu = s * (1.f / 128.f);
        s_stat[tid] = mu;
        s_stat[64 + tid] = rsqrtf(qv * (1.f / 128.f) - mu * mu + 1e-5f);
    }
    __syncthreads();                                   // bar2

    // ---- phase 4: h_norm -> s_hg (bf16 swizzled 256B rows; ef region dead) ----
    {
        float ge = g_edge[col], be = b_edge[col];
        #pragma unroll
        for (int mt = 0; mt < 4; ++mt)
            #pragma unroll
            for (int r = 0; r < 4; ++r) {
                int row = 16 * mt + 4 * q + r;
                float x = (h[mt][r] - s_stat[row]) * s_stat[64 + row] * ge + be;
                *(unsigned short*)(smem + row * 256 + ((col * 2) ^ ((row & 7) << 4))) = f2bf1(x);
            }
    }
    __syncthreads();                                   // bar3

    // ---- phase 5: FFN1 (drain hn to regs), gelu overwrites s_hg ----
    {
        ffrag a2[4] = {};
        #pragma unroll
        for (int kk = 0; kk < 4; ++kk) {
            bfrag bw = *(const bfrag*)(w1T + col * 128 + kk * 32 + 8 * q);
            #pragma unroll
            for (int mt = 0; mt < 4; ++mt) {
                int row = 16 * mt + c;
                bfrag x = *(const bfrag*)(smem + row * 256 + ((kk * 64 + 16 * q) ^ ((row & 7) << 4)));
                a2[mt] = __builtin_amdgcn_mfma_f32_16x16x32_bf16(x, bw, a2[mt], 0, 0, 0);
            }
        }
        __syncthreads();                               // bar4a: hn reads done
        float b1c = b1[col];
        #pragma unroll
        for (int mt = 0; mt < 4; ++mt)
            #pragma unroll
            for (int r = 0; r < 4; ++r) {
                int row = 16 * mt + 4 * q + r;
                float x = a2[mt][r] + b1c;
                float y = 0.7978845608028654f * x * (1.f + 0.044715f * x * x);
                float e;
                asm("v_exp_f32 %0, %1" : "=v"(e) : "v"(-2.885390081777927f * y));
                float rcp;
                asm("v_rcp_f32 %0, %1" : "=v"(rcp) : "v"(1.f + e));
                *(unsigned short*)(smem + row * 256 + ((col * 2) ^ ((row & 7) << 4))) = f2bf1(x * rcp);
            }
    }
    __syncthreads();                                   // bar4b

    // ---- phase 6: FFN2 + residual -> edge_output; masked aggregation ----
    {
        ffrag a3[4] = {};
        #pragma unroll
        for (int kk = 0; kk < 4; ++kk) {
            bfrag bw = *(const bfrag*)(w2T + col * 128 + kk * 32 + 8 * q);
            #pragma unroll
            for (int mt = 0; mt < 4; ++mt) {
                int row = 16 * mt + c;
                bfrag x = *(const bfrag*)(smem + row * 256 + ((kk * 64 + 16 * q) ^ ((row & 7) << 4)));
                a3[mt] = __builtin_amdgcn_mfma_f32_16x16x32_bf16(x, bw, a3[mt], 0, 0, 0);
            }
        }
        float b2c = b2[col];
        float* eo = out_edge + (size_t)rb * 128;
        float nvA = 0.f, nvB = 0.f;     // node A rows 0-31 (mt 0,1), node B rows 32-63
        #pragma unroll
        for (int mt = 0; mt < 4; ++mt)
            #pragma unroll
            for (int r = 0; r < 4; ++r) {
                int row = 16 * mt + 4 * q + r;
                float v = a3[mt][r] + b2c + h[mt][r];
                eo[row * 128 + col] = v;
                float mv = s_mask[row] * v;
                if (mt < 2) nvA += mv; else nvB += mv;
            }
        nvA += __shfl_xor(nvA, 16); nvA += __shfl_xor(nvA, 32);
        nvB += __shfl_xor(nvB, 16); nvB += __shfl_xor(nvB, 32);
        if (q == 0) { s_nv[col] = nvA; s_nv[128 + col] = nvB; }
    }
    __syncthreads();                                   // bar5

    // ---- phase 7: node LN (wave 0 -> node rb/32, wave 1 -> +1) ----
    if (w < 2) {
        float v0 = s_nv[w * 128 + l], v1 = s_nv[w * 128 + 64 + l];
        float s = v0 + v1, qv = v0 * v0 + v1 * v1;
        #pragma unroll
        for (int d = 1; d < 64; d <<= 1) { s += __shfl_xor(s, d); qv += __shfl_xor(qv, d); }
        float mu2 = s * (1.f / 128.f);
        float rstd = rsqrtf(qv * (1.f / 128.f) - mu2 * mu2 + 1e-5f);
        size_t nb = ((size_t)(rb >> 5) + w) * 128;
        out_node[nb + l]      = (v0 - mu2) * rstd * g_node[l]      + b_node[l];
        out_node[nb + 64 + l] = (v1 - mu2) * rstd * g_node[64 + l] + b_node[64 + l];
    }
}

extern "C" void kernel_launch(void* const* d_in, const int* in_sizes, int n_in,
                              void* d_out, int out_size, void* d_ws, size_t ws_size,
                              hipStream_t stream) {
    const float* ef     = (const float*)d_in[0];
    const int*   mask   = (const int*)d_in[1];
    const float* Wlin   = (const float*)d_in[2];
    const float* b_lin  = (const float*)d_in[3];
    const float* g_edge = (const float*)d_in[4];
    const float* b_edge = (const float*)d_in[5];
    const float* W1     = (const float*)d_in[6];
    const float* b1     = (const float*)d_in[7];
    const float* W2     = (const float*)d_in[8];
    const float* b2     = (const float*)d_in[9];
    const float* g_node = (const float*)d_in[10];
    const float* b_node = (const float*)d_in[11];

    int N = in_sizes[0] / (32 * 256);

    unsigned short* wlinT = (unsigned short*)d_ws;       // [128][256]
    unsigned short* w1T   = wlinT + 128 * 256;           // [128][128]
    unsigned short* w2T   = w1T + 128 * 128;             // [128][128]

    float* out_node = (float*)d_out;
    float* out_edge = out_node + (size_t)N * 128;

    prep_kernel<<<128, 256, 0, stream>>>(Wlin, W1, W2, wlinT, w1T, w2T);
    int nblocks = (N * 32 + 63) / 64;                    // N=20000 -> 10000 exact
    fused_kernel<<<nblocks, 512, 0, stream>>>(ef, mask, wlinT, w1T, w2T,
                                              b_lin, g_edge, b_edge, b1, b2,
                                              g_node, b_node, out_node, out_edge);
}

// Round 21
// 391.555 us; speedup vs baseline: 1.0075x; 1.0075x over previous
//
#include <hip/hip_runtime.h>

typedef __attribute__((ext_vector_type(8))) short bfrag;   // 8 x bf16
typedef __attribute__((ext_vector_type(4))) float ffrag;   // 4 x f32

struct alignas(16) U8v { unsigned int u[4]; };

__device__ __forceinline__ unsigned int cvt_pk_bf16(float lo, float hi) {
    unsigned int r;
    asm("v_cvt_pk_bf16_f32 %0, %1, %2" : "=v"(r) : "v"(lo), "v"(hi));
    return r;
}
__device__ __forceinline__ unsigned short f2bf1(float x) {
    return (unsigned short)cvt_pk_bf16(x, x);
}

// ---- prep: transpose + bf16-convert weights (r2-proven) ----
__global__ void prep_kernel(const float* __restrict__ Wlin,
                            const float* __restrict__ W1,
                            const float* __restrict__ W2,
                            unsigned short* __restrict__ wlinT,
                            unsigned short* __restrict__ w1T,
                            unsigned short* __restrict__ w2T) {
    int idx = blockIdx.x * 256 + threadIdx.x;           // 0..32767
    { int e = idx >> 7, h = idx & 127; wlinT[h * 256 + e] = f2bf1(Wlin[idx]); }
    if (idx < 16384) {
        int h = idx >> 7, f = idx & 127;
        w1T[f * 128 + h] = f2bf1(W1[idx]);
        w2T[f * 128 + h] = f2bf1(W2[idx]);
    }
}

// ---- fused kernel: 1 block = 2 nodes = 64 rows, 256 thr / 4 waves.
// Tests GROUP GRANULARITY at constant wave count: 4 blocks/CU x 4 waves
// (4 independent barrier groups) vs r18's 2 x 8. LDS 35.6KB (hn/gelu
// overlay the dead ef region; s_part dedicated -> no r15 race). Regs:
// h[4][2]+a2[4][2] sequential ~100 peak << 128 budget of (256,4) ->
// spill-impossible (r17/r20 lesson: 85-reg class always spills).
__global__ __launch_bounds__(256, 4) void fused_kernel(
    const float* __restrict__ ef, const int* __restrict__ mask,
    const unsigned short* __restrict__ wlinT,
    const unsigned short* __restrict__ w1T,
    const unsigned short* __restrict__ w2T,
    const float* __restrict__ b_lin, const float* __restrict__ g_edge,
    const float* __restrict__ b_edge, const float* __restrict__ b1,
    const float* __restrict__ b2, const float* __restrict__ g_node,
    const float* __restrict__ b_node,
    float* __restrict__ out_node, float* __restrict__ out_edge) {

    // phase1-2: ef bf16 [64 rows x 512B, swizzled] @0..32768
    // phase4+:  s_hg bf16 [64 rows x 256B, swizzled] @0..16384 (ef dead)
    __shared__ char  smem[32768];
    __shared__ float s_part[512];   // DEDICATED: 4 waves x 64 rows x {sum,sq}
    __shared__ float s_stat[128];   // [0:64) mu, [64:128) rstd
    __shared__ float s_mask[64];

    float* s_nv = s_part;           // overlay: s_part dead before s_nv written

    const int tid = threadIdx.x;
    const int w = tid >> 6, l = tid & 63, q = l >> 4, c = l & 15;
    const int col0 = 32 * w + c, col1 = 32 * w + 16 + c;
    const int rb = blockIdx.x * 64;                  // 640000/64 = 10000 exact
    const float* efb = ef + (size_t)rb * 256;

    if (tid < 64) s_mask[tid] = (mask[(size_t)rb + tid] != 0) ? 1.f : 0.f;

    // ---- phase 1: stage 64 rows of ef -> bf16 LDS (swizzled 16B slots) ----
    #pragma unroll
    for (int i = 0; i < 8; ++i) {
        int s = i * 256 + tid;          // 2048 slots (64 rows x 32)
        int row = s >> 5, cs = s & 31;
        const float4* p = (const float4*)(efb + (size_t)s * 8);
        float4 v0 = p[0], v1 = p[1];
        U8v u;
        u.u[0] = cvt_pk_bf16(v0.x, v0.y); u.u[1] = cvt_pk_bf16(v0.z, v0.w);
        u.u[2] = cvt_pk_bf16(v1.x, v1.y); u.u[3] = cvt_pk_bf16(v1.z, v1.w);
        *(U8v*)(smem + row * 512 + ((cs * 16) ^ ((row & 7) << 4))) = u;
    }
    __syncthreads();                                   // bar0

    // ---- phase 2: h = ef @ Wlin + b_lin (M=64, K=256, wave's 32 cols) ----
    ffrag h[4][2] = {};
    #pragma unroll
    for (int kk = 0; kk < 8; ++kk) {
        bfrag bw0 = *(const bfrag*)(wlinT + col0 * 256 + kk * 32 + 8 * q);
        bfrag bw1 = *(const bfrag*)(wlinT + col1 * 256 + kk * 32 + 8 * q);
        #pragma unroll
        for (int mt = 0; mt < 4; ++mt) {
            int row = 16 * mt + c;
            bfrag a = *(const bfrag*)(smem + row * 512 + ((kk * 64 + q * 16) ^ ((row & 7) << 4)));
            h[mt][0] = __builtin_amdgcn_mfma_f32_16x16x32_bf16(a, bw0, h[mt][0], 0, 0, 0);
            h[mt][1] = __builtin_amdgcn_mfma_f32_16x16x32_bf16(a, bw1, h[mt][1], 0, 0, 0);
        }
    }
    {
        float bl0 = b_lin[col0], bl1 = b_lin[col1];
        #pragma unroll
        for (int mt = 0; mt < 4; ++mt)
            #pragma unroll
            for (int r = 0; r < 4; ++r) { h[mt][0][r] += bl0; h[mt][1][r] += bl1; }
    }

    // ---- phase 3: edge-LN stats (both col-frags; in-wave over c, cross-wave LDS) ----
    #pragma unroll
    for (int mt = 0; mt < 4; ++mt)
        #pragma unroll
        for (int r = 0; r < 4; ++r) {
            float s  = h[mt][0][r] + h[mt][1][r];
            float qv = h[mt][0][r] * h[mt][0][r] + h[mt][1][r] * h[mt][1][r];
            #pragma unroll
            for (int d = 1; d < 16; d <<= 1) { s += __shfl_xor(s, d); qv += __shfl_xor(qv, d); }
            if (c == 0) {
                int row = 16 * mt + 4 * q + r;
                s_part[w * 128 + row * 2]     = s;
                s_part[w * 128 + row * 2 + 1] = qv;
            }
        }
    __syncthreads();                                   // bar1 (all ef reads done)
    if (tid < 64) {
        float s = 0.f, qv = 0.f;
        #pragma unroll
        for (int ww = 0; ww < 4; ++ww) { s += s_part[ww * 128 + tid * 2]; qv += s_part[ww * 128 + tid * 2 + 1]; }
        float mu = s * (1.f / 128.f);
        s_stat[tid] = mu;
        s_stat[64 + tid] = rsqrtf(qv * (1.f / 128.f) - mu * mu + 1e-5f);
    }
    __syncthreads();                                   // bar2

    // ---- phase 4: h_norm -> s_hg overlay (bf16, swizzled 256B rows) ----
    {
        float ge0 = g_edge[col0], ge1 = g_edge[col1];
        float be0 = b_edge[col0], be1 = b_edge[col1];
        #pragma unroll
        for (int mt = 0; mt < 4; ++mt)
            #pragma unroll
            for (int r = 0; r < 4; ++r) {
                int row = 16 * mt + 4 * q + r;
                float mu = s_stat[row], rs = s_stat[64 + row];
                *(unsigned short*)(smem + row * 256 + ((col0 * 2) ^ ((row & 7) << 4))) =
                    f2bf1((h[mt][0][r] - mu) * rs * ge0 + be0);
                *(unsigned short*)(smem + row * 256 + ((col1 * 2) ^ ((row & 7) << 4))) =
                    f2bf1((h[mt][1][r] - mu) * rs * ge1 + be1);
            }
    }
    __syncthreads();                                   // bar3

    // ---- phase 5: FFN1 (drain hn to regs), gelu overwrites s_hg ----
    {
        ffrag a2[4][2] = {};
        #pragma unroll
        for (int kk = 0; kk < 4; ++kk) {
            bfrag bw0 = *(const bfrag*)(w1T + col0 * 128 + kk * 32 + 8 * q);
            bfrag bw1 = *(const bfrag*)(w1T + col1 * 128 + kk * 32 + 8 * q);
            #pragma unroll
            for (int mt = 0; mt < 4; ++mt) {
                int row = 16 * mt + c;
                bfrag x = *(const bfrag*)(smem + row * 256 + ((kk * 64 + 16 * q) ^ ((row & 7) << 4)));
                a2[mt][0] = __builtin_amdgcn_mfma_f32_16x16x32_bf16(x, bw0, a2[mt][0], 0, 0, 0);
                a2[mt][1] = __builtin_amdgcn_mfma_f32_16x16x32_bf16(x, bw1, a2[mt][1], 0, 0, 0);
            }
        }
        __syncthreads();                               // bar4a: hn reads done
        float b10 = b1[col0], b11 = b1[col1];
        #pragma unroll
        for (int mt = 0; mt < 4; ++mt)
            #pragma unroll
            for (int j = 0; j < 2; ++j) {
                int col = j ? col1 : col0;
                float bb = j ? b11 : b10;
                #pragma unroll
                for (int r = 0; r < 4; ++r) {
                    int row = 16 * mt + 4 * q + r;
                    float x = a2[mt][j][r] + bb;
                    float y = 0.7978845608028654f * x * (1.f + 0.044715f * x * x);
                    float e;
                    asm("v_exp_f32 %0, %1" : "=v"(e) : "v"(-2.885390081777927f * y));
                    float rcp;
                    asm("v_rcp_f32 %0, %1" : "=v"(rcp) : "v"(1.f + e));
                    *(unsigned short*)(smem + row * 256 + ((col * 2) ^ ((row & 7) << 4))) = f2bf1(x * rcp);
                }
            }
    }
    __syncthreads();                                   // bar4b

    // ---- phase 6: FFN2 + residual -> edge_output; masked aggregation ----
    {
        ffrag a3[4][2] = {};
        #pragma unroll
        for (int kk = 0; kk < 4; ++kk) {
            bfrag bw0 = *(const bfrag*)(w2T + col0 * 128 + kk * 32 + 8 * q);
            bfrag bw1 = *(const bfrag*)(w2T + col1 * 128 + kk * 32 + 8 * q);
            #pragma unroll
            for (int mt = 0; mt < 4; ++mt) {
                int row = 16 * mt + c;
                bfrag x = *(const bfrag*)(smem + row * 256 + ((kk * 64 + 16 * q) ^ ((row & 7) << 4)));
                a3[mt][0] = __builtin_amdgcn_mfma_f32_16x16x32_bf16(x, bw0, a3[mt][0], 0, 0, 0);
                a3[mt][1] = __builtin_amdgcn_mfma_f32_16x16x32_bf16(x, bw1, a3[mt][1], 0, 0, 0);
            }
        }
        float b20 = b2[col0], b21 = b2[col1];
        float* eo = out_edge + (size_t)rb * 128;
        float nvA0 = 0.f, nvA1 = 0.f, nvB0 = 0.f, nvB1 = 0.f;
        #pragma unroll
        for (int mt = 0; mt < 4; ++mt)
            #pragma unroll
            for (int r = 0; r < 4; ++r) {
                int row = 16 * mt + 4 * q + r;
                float mk = s_mask[row];
                float v0 = a3[mt][0][r] + b20 + h[mt][0][r];
                float v1 = a3[mt][1][r] + b21 + h[mt][1][r];
                eo[row * 128 + col0] = v0;
                eo[row * 128 + col1] = v1;
                if (mt < 2) { nvA0 += mk * v0; nvA1 += mk * v1; }
                else        { nvB0 += mk * v0; nvB1 += mk * v1; }
            }
        nvA0 += __shfl_xor(nvA0, 16); nvA0 += __shfl_xor(nvA0, 32);
        nvA1 += __shfl_xor(nvA1, 16); nvA1 += __shfl_xor(nvA1, 32);
        nvB0 += __shfl_xor(nvB0, 16); nvB0 += __shfl_xor(nvB0, 32);
        nvB1 += __shfl_xor(nvB1, 16); nvB1 += __shfl_xor(nvB1, 32);
        if (q == 0) {
            s_nv[col0] = nvA0;       s_nv[col1] = nvA1;
            s_nv[128 + col0] = nvB0; s_nv[128 + col1] = nvB1;
        }
    }
    __syncthreads();                                   // bar5

    // ---- phase 7: node LN (wave 0 -> node rb/32, wave 1 -> +1) ----
    if (w < 2) {
        float v0 = s_nv[w * 128 + l], v1 = s_nv[w * 128 + 64 + l];
        float s = v0 + v1, qv = v0 * v0 + v1 * v1;
        #pragma unroll
        for (int d = 1; d < 64; d <<= 1) { s += __shfl_xor(s, d); qv += __shfl_xor(qv, d); }
        float mu2 = s * (1.f / 128.f);
        float rstd = rsqrtf(qv * (1.f / 128.f) - mu2 * mu2 + 1e-5f);
        size_t nb = ((size_t)(rb >> 5) + w) * 128;
        out_node[nb + l]      = (v0 - mu2) * rstd * g_node[l]      + b_node[l];
        out_node[nb + 64 + l] = (v1 - mu2) * rstd * g_node[64 + l] + b_node[64 + l];
    }
}

extern "C" void kernel_launch(void* const* d_in, const int* in_sizes, int n_in,
                              void* d_out, int out_size, void* d_ws, size_t ws_size,
                              hipStream_t stream) {
    const float* ef     = (const float*)d_in[0];
    const int*   mask   = (const int*)d_in[1];
    const float* Wlin   = (const float*)d_in[2];
    const float* b_lin  = (const float*)d_in[3];
    const float* g_edge = (const float*)d_in[4];
    const float* b_edge = (const float*)d_in[5];
    const float* W1     = (const float*)d_in[6];
    const float* b1     = (const float*)d_in[7];
    const float* W2     = (const float*)d_in[8];
    const float* b2     = (const float*)d_in[9];
    const float* g_node = (const float*)d_in[10];
    const float* b_node = (const float*)d_in[11];

    int N = in_sizes[0] / (32 * 256);

    unsigned short* wlinT = (unsigned short*)d_ws;       // [128][256]
    unsigned short* w1T   = wlinT + 128 * 256;           // [128][128]
    unsigned short* w2T   = w1T + 128 * 128;             // [128][128]

    float* out_node = (float*)d_out;
    float* out_edge = out_node + (size_t)N * 128;

    prep_kernel<<<128, 256, 0, stream>>>(Wlin, W1, W2, wlinT, w1T, w2T);
    int nblocks = (N * 32 + 63) / 64;                    // N=20000 -> 10000 exact
    fused_kernel<<<nblocks, 256, 0, stream>>>(ef, mask, wlinT, w1T, w2T,
                                              b_lin, g_edge, b_edge, b1, b2,
                                              g_node, b_node, out_node, out_edge);
}

// Round 22
// 325.092 us; speedup vs baseline: 1.2135x; 1.2044x over previous
//
#include <hip/hip_runtime.h>

typedef __attribute__((ext_vector_type(8))) short bfrag;   // 8 x bf16
typedef __attribute__((ext_vector_type(4))) float ffrag;   // 4 x f32

struct alignas(16) U8v { unsigned int u[4]; };

__device__ __forceinline__ unsigned int cvt_pk_bf16(float lo, float hi) {
    unsigned int r;
    asm("v_cvt_pk_bf16_f32 %0, %1, %2" : "=v"(r) : "v"(lo), "v"(hi));
    return r;
}
__device__ __forceinline__ unsigned short f2bf1(float x) {
    return (unsigned short)cvt_pk_bf16(x, x);
}

// ---- prep1: wlinT/w2T transpose + bf16 (r2-proven) ----
__global__ void prep1(const float* __restrict__ Wlin, const float* __restrict__ W2,
                      unsigned short* __restrict__ wlinT, unsigned short* __restrict__ w2T) {
    int idx = blockIdx.x * 256 + threadIdx.x;           // 0..32767
    { int e = idx >> 7, h = idx & 127; wlinT[h * 256 + e] = f2bf1(Wlin[idx]); }
    if (idx < 16384) { int a = idx >> 7, b = idx & 127; w2T[b * 128 + a] = f2bf1(W2[idx]); }
}

// ---- prep2: fold edge-LN affine into W1 (r8 algebra, verified):
// hn@W1 = z@(g_edge⊙W1) + b_edge@W1, z=(h-mu)*rs.
// w1gT[f][h] = bf16(g_edge[h]*W1[h][f]); b1f[f] = b1[f] + sum_h b_edge[h]*W1[h][f]
__global__ void prep2(const float* __restrict__ W1, const float* __restrict__ g_edge,
                      const float* __restrict__ b_edge, const float* __restrict__ b1,
                      unsigned short* __restrict__ w1gT, float* __restrict__ b1f) {
    int f = threadIdx.x;
    float s = b1[f];
    for (int h = 0; h < 128; ++h) {
        float wv = W1[h * 128 + f];
        w1gT[f * 128 + h] = f2bf1(g_edge[h] * wv);
        s += b_edge[h] * wv;
    }
    b1f[f] = s;
}

// ---- fused kernel: 1 block = 4 nodes = 128 rows, 512 thr / 8 waves.
// = r18 (306us best; r16-family) + LN-affine fold: phase 4 writes plain
// z=(h-mu)*rs (saves 2 VALU x 32 vals/thread + g/b const loads). Matrix of
// {rows, residency, granularity, orientation, pipelining} fully explored
// r4-r21; only this cell is spill-free AND amortized. VALU is top pipe (23%).
__global__ __launch_bounds__(512, 4) void fused_kernel(
    const float* __restrict__ ef, const int* __restrict__ mask,
    const unsigned short* __restrict__ wlinT,
    const unsigned short* __restrict__ w1gT,
    const unsigned short* __restrict__ w2T,
    const float* __restrict__ b_lin, const float* __restrict__ b1f,
    const float* __restrict__ b2, const float* __restrict__ g_node,
    const float* __restrict__ b_node,
    float* __restrict__ out_node, float* __restrict__ out_edge) {

    // phase1-2: ef bf16 [128 rows x 512B, swizzled] @0..65536
    // phase4+:  s_hn bf16 [128 x 272B] @0..34816, s_g @34816..69632
    __shared__ char  smem[69632];
    __shared__ float s_part[2048];  // DEDICATED: 8 waves x 128 rows x {sum,sq}
    __shared__ float s_stat[256];   // [0:128) mu, [128:256) rstd
    __shared__ float s_mask[128];

    float* s_nv = s_part;           // overlay: s_part dead before s_nv written
    unsigned short* s_hn = (unsigned short*)smem;              // stride 136 shorts
    unsigned short* s_g  = (unsigned short*)(smem + 34816);    // stride 136 shorts

    const int tid = threadIdx.x;
    const int w = tid >> 6, l = tid & 63, q = l >> 4, c = l & 15;
    const int col = 16 * w + c;
    const int rb = blockIdx.x * 128;                 // 4 nodes, N=20000 -> exact
    const float* efb = ef + (size_t)rb * 256;

    if (tid < 128) s_mask[tid] = (mask[(size_t)rb + tid] != 0) ? 1.f : 0.f;

    // ---- phase 1: stage 128 rows of ef -> bf16 LDS (swizzled 16B slots) ----
    #pragma unroll
    for (int i = 0; i < 8; ++i) {
        int s = i * 512 + tid;          // 4096 slots (128 rows x 32)
        int row = s >> 5, cs = s & 31;
        const float4* p = (const float4*)(efb + (size_t)s * 8);
        float4 v0 = p[0], v1 = p[1];
        U8v u;
        u.u[0] = cvt_pk_bf16(v0.x, v0.y); u.u[1] = cvt_pk_bf16(v0.z, v0.w);
        u.u[2] = cvt_pk_bf16(v1.x, v1.y); u.u[3] = cvt_pk_bf16(v1.z, v1.w);
        *(U8v*)(smem + row * 512 + ((cs * 16) ^ ((row & 7) << 4))) = u;
    }
    __syncthreads();                                   // bar0

    // ---- phase 2: h = ef @ Wlin + b_lin (M=128, K=256, wave's 16 cols) ----
    ffrag h[8] = {};
    #pragma unroll
    for (int kk = 0; kk < 8; ++kk) {
        bfrag bw = *(const bfrag*)(wlinT + col * 256 + kk * 32 + 8 * q);
        #pragma unroll
        for (int mt = 0; mt < 8; ++mt) {
            int row = 16 * mt + c;
            bfrag a = *(const bfrag*)(smem + row * 512 + ((kk * 64 + q * 16) ^ ((row & 7) << 4)));
            h[mt] = __builtin_amdgcn_mfma_f32_16x16x32_bf16(a, bw, h[mt], 0, 0, 0);
        }
    }
    {
        float blc = b_lin[col];
        #pragma unroll
        for (int mt = 0; mt < 8; ++mt)
            #pragma unroll
            for (int r = 0; r < 4; ++r) h[mt][r] += blc;
    }

    // ---- phase 3: edge-LN stats -> dedicated s_part ----
    #pragma unroll
    for (int mt = 0; mt < 8; ++mt)
        #pragma unroll
        for (int r = 0; r < 4; ++r) {
            float s = h[mt][r], qv = h[mt][r] * h[mt][r];
            #pragma unroll
            for (int d = 1; d < 16; d <<= 1) { s += __shfl_xor(s, d); qv += __shfl_xor(qv, d); }
            if (c == 0) {
                int row = 16 * mt + 4 * q + r;
                s_part[w * 256 + row * 2]     = s;
                s_part[w * 256 + row * 2 + 1] = qv;
            }
        }
    __syncthreads();                                   // bar1 (all ef reads done)
    if (tid < 128) {
        float s = 0.f, qv = 0.f;
        #pragma unroll
        for (int ww = 0; ww < 8; ++ww) { s += s_part[ww * 256 + tid * 2]; qv += s_part[ww * 256 + tid * 2 + 1]; }
        float mu = s * (1.f / 128.f);
        s_stat[tid] = mu;
        s_stat[128 + tid] = rsqrtf(qv * (1.f / 128.f) - mu * mu + 1e-5f);
    }
    __syncthreads();                                   // bar2

    // ---- phase 4: z = (h-mu)*rs -> bf16 LDS (affine folded into W1g/b1f) ----
    #pragma unroll
    for (int mt = 0; mt < 8; ++mt)
        #pragma unroll
        for (int r = 0; r < 4; ++r) {
            int row = 16 * mt + 4 * q + r;
            float x = (h[mt][r] - s_stat[row]) * s_stat[128 + row];
            s_hn[row * 136 + col] = f2bf1(x);
        }
    __syncthreads();                                   // bar3

    // ---- phase 5: FFN1 (W1g) + gelu (M=128, K=128) ----
    {
        ffrag a2[8] = {};
        #pragma unroll
        for (int kk = 0; kk < 4; ++kk) {
            bfrag bw = *(const bfrag*)(w1gT + col * 128 + kk * 32 + 8 * q);
            #pragma unroll
            for (int mt = 0; mt < 8; ++mt) {
                bfrag x = *(const bfrag*)(s_hn + (16 * mt + c) * 136 + kk * 32 + 8 * q);
                a2[mt] = __builtin_amdgcn_mfma_f32_16x16x32_bf16(x, bw, a2[mt], 0, 0, 0);
            }
        }
        float b1c = b1f[col];
        #pragma unroll
        for (int mt = 0; mt < 8; ++mt)
            #pragma unroll
            for (int r = 0; r < 4; ++r) {
                int row = 16 * mt + 4 * q + r;
                float x = a2[mt][r] + b1c;
                float y = 0.7978845608028654f * x * (1.f + 0.044715f * x * x);
                float e;
                asm("v_exp_f32 %0, %1" : "=v"(e) : "v"(-2.885390081777927f * y));
                float rcp;
                asm("v_rcp_f32 %0, %1" : "=v"(rcp) : "v"(1.f + e));
                s_g[row * 136 + col] = f2bf1(x * rcp);
            }
    }
    __syncthreads();                                   // bar4

    // ---- phase 6: FFN2 + residual -> edge_output; masked aggregation ----
    {
        ffrag a3[8] = {};
        #pragma unroll
        for (int kk = 0; kk < 4; ++kk) {
            bfrag bw = *(const bfrag*)(w2T + col * 128 + kk * 32 + 8 * q);
            #pragma unroll
            for (int mt = 0; mt < 8; ++mt) {
                bfrag x = *(const bfrag*)(s_g + (16 * mt + c) * 136 + kk * 32 + 8 * q);
                a3[mt] = __builtin_amdgcn_mfma_f32_16x16x32_bf16(x, bw, a3[mt], 0, 0, 0);
            }
        }
        float b2c = b2[col];
        float* eo = out_edge + (size_t)rb * 128;
        float nv0 = 0.f, nv1 = 0.f, nv2 = 0.f, nv3 = 0.f;   // per-node partials
        #pragma unroll
        for (int mt = 0; mt < 8; ++mt)
            #pragma unroll
            for (int r = 0; r < 4; ++r) {
                int row = 16 * mt + 4 * q + r;
                float v = a3[mt][r] + b2c + h[mt][r];
                eo[row * 128 + col] = v;
                float mv = s_mask[row] * v;
                if (mt < 2)      nv0 += mv;
                else if (mt < 4) nv1 += mv;
                else if (mt < 6) nv2 += mv;
                else             nv3 += mv;
            }
        nv0 += __shfl_xor(nv0, 16); nv0 += __shfl_xor(nv0, 32);
        nv1 += __shfl_xor(nv1, 16); nv1 += __shfl_xor(nv1, 32);
        nv2 += __shfl_xor(nv2, 16); nv2 += __shfl_xor(nv2, 32);
        nv3 += __shfl_xor(nv3, 16); nv3 += __shfl_xor(nv3, 32);
        if (q == 0) {
            s_nv[col]       = nv0;
            s_nv[128 + col] = nv1;
            s_nv[256 + col] = nv2;
            s_nv[384 + col] = nv3;
        }
    }
    __syncthreads();                                   // bar5

    // ---- phase 7: node LN (waves 0-3 -> nodes 0-3) ----
    if (w < 4) {
        float v0 = s_nv[w * 128 + l], v1 = s_nv[w * 128 + 64 + l];
        float s = v0 + v1, qv = v0 * v0 + v1 * v1;
        #pragma unroll
        for (int d = 1; d < 64; d <<= 1) { s += __shfl_xor(s, d); qv += __shfl_xor(qv, d); }
        float mu2 = s * (1.f / 128.f);
        float rstd = rsqrtf(qv * (1.f / 128.f) - mu2 * mu2 + 1e-5f);
        size_t nb = ((size_t)(rb >> 5) + w) * 128;
        out_node[nb + l]      = (v0 - mu2) * rstd * g_node[l]      + b_node[l];
        out_node[nb + 64 + l] = (v1 - mu2) * rstd * g_node[64 + l] + b_node[64 + l];
    }
}

extern "C" void kernel_launch(void* const* d_in, const int* in_sizes, int n_in,
                              void* d_out, int out_size, void* d_ws, size_t ws_size,
                              hipStream_t stream) {
    const float* ef     = (const float*)d_in[0];
    const int*   mask   = (const int*)d_in[1];
    const float* Wlin   = (const float*)d_in[2];
    const float* b_lin  = (const float*)d_in[3];
    const float* g_edge = (const float*)d_in[4];
    const float* b_edge = (const float*)d_in[5];
    const float* W1     = (const float*)d_in[6];
    const float* b1     = (const float*)d_in[7];
    const float* W2     = (const float*)d_in[8];
    const float* b2     = (const float*)d_in[9];
    const float* g_node = (const float*)d_in[10];
    const float* b_node = (const float*)d_in[11];

    int N = in_sizes[0] / (32 * 256);

    unsigned short* wlinT = (unsigned short*)d_ws;          // [128][256] bf16
    unsigned short* w1gT  = wlinT + 128 * 256;              // [128][128] bf16 (g-folded)
    unsigned short* w2T   = w1gT + 128 * 128;               // [128][128] bf16
    float*          b1f   = (float*)(w2T + 128 * 128);      // [128] f32

    float* out_node = (float*)d_out;
    float* out_edge = out_node + (size_t)N * 128;

    prep1<<<128, 256, 0, stream>>>(Wlin, W2, wlinT, w2T);
    prep2<<<1, 128, 0, stream>>>(W1, g_edge, b_edge, b1, w1gT, b1f);
    int nblocks = (N * 32 + 127) / 128;                     // N=20000 -> 5000 exact
    fused_kernel<<<nblocks, 512, 0, stream>>>(ef, mask, wlinT, w1gT, w2T,
                                              b_lin, b1f, b2, g_node, b_node,
                                              out_node, out_edge);
}

// Round 23
// 300.845 us; speedup vs baseline: 1.3113x; 1.0806x over previous
//
#include <hip/hip_runtime.h>

typedef __attribute__((ext_vector_type(8))) short bfrag;   // 8 x bf16
typedef __attribute__((ext_vector_type(4))) float ffrag;   // 4 x f32

struct alignas(16) U8v { unsigned int u[4]; };

__device__ __forceinline__ unsigned int cvt_pk_bf16(float lo, float hi) {
    unsigned int r;
    asm("v_cvt_pk_bf16_f32 %0, %1, %2" : "=v"(r) : "v"(lo), "v"(hi));
    return r;
}
__device__ __forceinline__ unsigned short f2bf1(float x) {
    return (unsigned short)cvt_pk_bf16(x, x);
}

// ---- prep1: wlinT/w2T transpose + bf16 (r2-proven) ----
__global__ void prep1(const float* __restrict__ Wlin, const float* __restrict__ W2,
                      unsigned short* __restrict__ wlinT, unsigned short* __restrict__ w2T) {
    int idx = blockIdx.x * 256 + threadIdx.x;           // 0..32767
    { int e = idx >> 7, h = idx & 127; wlinT[h * 256 + e] = f2bf1(Wlin[idx]); }
    if (idx < 16384) { int a = idx >> 7, b = idx & 127; w2T[b * 128 + a] = f2bf1(W2[idx]); }
}

// ---- prep2 (r22 lesson: PARALLEL — the 1-block serial version cost ~20-30us
// on the graph's critical path). 128 blocks (f) x 128 threads (h):
// w1gT[f][h] = bf16(g_edge[h]*W1[h][f]); b1f[f] = b1[f] + sum_h b_edge[h]*W1[h][f]
__global__ void prep2(const float* __restrict__ W1, const float* __restrict__ g_edge,
                      const float* __restrict__ b_edge, const float* __restrict__ b1,
                      unsigned short* __restrict__ w1gT, float* __restrict__ b1f) {
    const int f = blockIdx.x, h = threadIdx.x;
    __shared__ float red[2];
    float wv = W1[h * 128 + f];
    w1gT[f * 128 + h] = f2bf1(g_edge[h] * wv);
    float p = b_edge[h] * wv;
    #pragma unroll
    for (int d = 1; d < 64; d <<= 1) p += __shfl_xor(p, d);
    if ((h & 63) == 0) red[h >> 6] = p;
    __syncthreads();
    if (h == 0) b1f[f] = b1[f] + red[0] + red[1];
}

// ---- fused kernel: byte-identical to r22 (r18 structure + LN-affine fold).
// 1 block = 4 nodes = 128 rows, 512 thr / 8 waves, 6 barriers.
__global__ __launch_bounds__(512, 4) void fused_kernel(
    const float* __restrict__ ef, const int* __restrict__ mask,
    const unsigned short* __restrict__ wlinT,
    const unsigned short* __restrict__ w1gT,
    const unsigned short* __restrict__ w2T,
    const float* __restrict__ b_lin, const float* __restrict__ b1f,
    const float* __restrict__ b2, const float* __restrict__ g_node,
    const float* __restrict__ b_node,
    float* __restrict__ out_node, float* __restrict__ out_edge) {

    // phase1-2: ef bf16 [128 rows x 512B, swizzled] @0..65536
    // phase4+:  s_hn bf16 [128 x 272B] @0..34816, s_g @34816..69632
    __shared__ char  smem[69632];
    __shared__ float s_part[2048];  // DEDICATED: 8 waves x 128 rows x {sum,sq}
    __shared__ float s_stat[256];   // [0:128) mu, [128:256) rstd
    __shared__ float s_mask[128];

    float* s_nv = s_part;           // overlay: s_part dead before s_nv written
    unsigned short* s_hn = (unsigned short*)smem;              // stride 136 shorts
    unsigned short* s_g  = (unsigned short*)(smem + 34816);    // stride 136 shorts

    const int tid = threadIdx.x;
    const int w = tid >> 6, l = tid & 63, q = l >> 4, c = l & 15;
    const int col = 16 * w + c;
    const int rb = blockIdx.x * 128;                 // 4 nodes, N=20000 -> exact
    const float* efb = ef + (size_t)rb * 256;

    if (tid < 128) s_mask[tid] = (mask[(size_t)rb + tid] != 0) ? 1.f : 0.f;

    // ---- phase 1: stage 128 rows of ef -> bf16 LDS (swizzled 16B slots) ----
    #pragma unroll
    for (int i = 0; i < 8; ++i) {
        int s = i * 512 + tid;          // 4096 slots (128 rows x 32)
        int row = s >> 5, cs = s & 31;
        const float4* p = (const float4*)(efb + (size_t)s * 8);
        float4 v0 = p[0], v1 = p[1];
        U8v u;
        u.u[0] = cvt_pk_bf16(v0.x, v0.y); u.u[1] = cvt_pk_bf16(v0.z, v0.w);
        u.u[2] = cvt_pk_bf16(v1.x, v1.y); u.u[3] = cvt_pk_bf16(v1.z, v1.w);
        *(U8v*)(smem + row * 512 + ((cs * 16) ^ ((row & 7) << 4))) = u;
    }
    __syncthreads();                                   // bar0

    // ---- phase 2: h = ef @ Wlin + b_lin (M=128, K=256, wave's 16 cols) ----
    ffrag h[8] = {};
    #pragma unroll
    for (int kk = 0; kk < 8; ++kk) {
        bfrag bw = *(const bfrag*)(wlinT + col * 256 + kk * 32 + 8 * q);
        #pragma unroll
        for (int mt = 0; mt < 8; ++mt) {
            int row = 16 * mt + c;
            bfrag a = *(const bfrag*)(smem + row * 512 + ((kk * 64 + q * 16) ^ ((row & 7) << 4)));
            h[mt] = __builtin_amdgcn_mfma_f32_16x16x32_bf16(a, bw, h[mt], 0, 0, 0);
        }
    }
    {
        float blc = b_lin[col];
        #pragma unroll
        for (int mt = 0; mt < 8; ++mt)
            #pragma unroll
            for (int r = 0; r < 4; ++r) h[mt][r] += blc;
    }

    // ---- phase 3: edge-LN stats -> dedicated s_part ----
    #pragma unroll
    for (int mt = 0; mt < 8; ++mt)
        #pragma unroll
        for (int r = 0; r < 4; ++r) {
            float s = h[mt][r], qv = h[mt][r] * h[mt][r];
            #pragma unroll
            for (int d = 1; d < 16; d <<= 1) { s += __shfl_xor(s, d); qv += __shfl_xor(qv, d); }
            if (c == 0) {
                int row = 16 * mt + 4 * q + r;
                s_part[w * 256 + row * 2]     = s;
                s_part[w * 256 + row * 2 + 1] = qv;
            }
        }
    __syncthreads();                                   // bar1 (all ef reads done)
    if (tid < 128) {
        float s = 0.f, qv = 0.f;
        #pragma unroll
        for (int ww = 0; ww < 8; ++ww) { s += s_part[ww * 256 + tid * 2]; qv += s_part[ww * 256 + tid * 2 + 1]; }
        float mu = s * (1.f / 128.f);
        s_stat[tid] = mu;
        s_stat[128 + tid] = rsqrtf(qv * (1.f / 128.f) - mu * mu + 1e-5f);
    }
    __syncthreads();                                   // bar2

    // ---- phase 4: z = (h-mu)*rs -> bf16 LDS (affine folded into W1g/b1f) ----
    #pragma unroll
    for (int mt = 0; mt < 8; ++mt)
        #pragma unroll
        for (int r = 0; r < 4; ++r) {
            int row = 16 * mt + 4 * q + r;
            float x = (h[mt][r] - s_stat[row]) * s_stat[128 + row];
            s_hn[row * 136 + col] = f2bf1(x);
        }
    __syncthreads();                                   // bar3

    // ---- phase 5: FFN1 (W1g) + gelu (M=128, K=128) ----
    {
        ffrag a2[8] = {};
        #pragma unroll
        for (int kk = 0; kk < 4; ++kk) {
            bfrag bw = *(const bfrag*)(w1gT + col * 128 + kk * 32 + 8 * q);
            #pragma unroll
            for (int mt = 0; mt < 8; ++mt) {
                bfrag x = *(const bfrag*)(s_hn + (16 * mt + c) * 136 + kk * 32 + 8 * q);
                a2[mt] = __builtin_amdgcn_mfma_f32_16x16x32_bf16(x, bw, a2[mt], 0, 0, 0);
            }
        }
        float b1c = b1f[col];
        #pragma unroll
        for (int mt = 0; mt < 8; ++mt)
            #pragma unroll
            for (int r = 0; r < 4; ++r) {
                int row = 16 * mt + 4 * q + r;
                float x = a2[mt][r] + b1c;
                float y = 0.7978845608028654f * x * (1.f + 0.044715f * x * x);
                float e;
                asm("v_exp_f32 %0, %1" : "=v"(e) : "v"(-2.885390081777927f * y));
                float rcp;
                asm("v_rcp_f32 %0, %1" : "=v"(rcp) : "v"(1.f + e));
                s_g[row * 136 + col] = f2bf1(x * rcp);
            }
    }
    __syncthreads();                                   // bar4

    // ---- phase 6: FFN2 + residual -> edge_output; masked aggregation ----
    {
        ffrag a3[8] = {};
        #pragma unroll
        for (int kk = 0; kk < 4; ++kk) {
            bfrag bw = *(const bfrag*)(w2T + col * 128 + kk * 32 + 8 * q);
            #pragma unroll
            for (int mt = 0; mt < 8; ++mt) {
                bfrag x = *(const bfrag*)(s_g + (16 * mt + c) * 136 + kk * 32 + 8 * q);
                a3[mt] = __builtin_amdgcn_mfma_f32_16x16x32_bf16(x, bw, a3[mt], 0, 0, 0);
            }
        }
        float b2c = b2[col];
        float* eo = out_edge + (size_t)rb * 128;
        float nv0 = 0.f, nv1 = 0.f, nv2 = 0.f, nv3 = 0.f;   // per-node partials
        #pragma unroll
        for (int mt = 0; mt < 8; ++mt)
            #pragma unroll
            for (int r = 0; r < 4; ++r) {
                int row = 16 * mt + 4 * q + r;
                float v = a3[mt][r] + b2c + h[mt][r];
                eo[row * 128 + col] = v;
                float mv = s_mask[row] * v;
                if (mt < 2)      nv0 += mv;
                else if (mt < 4) nv1 += mv;
                else if (mt < 6) nv2 += mv;
                else             nv3 += mv;
            }
        nv0 += __shfl_xor(nv0, 16); nv0 += __shfl_xor(nv0, 32);
        nv1 += __shfl_xor(nv1, 16); nv1 += __shfl_xor(nv1, 32);
        nv2 += __shfl_xor(nv2, 16); nv2 += __shfl_xor(nv2, 32);
        nv3 += __shfl_xor(nv3, 16); nv3 += __shfl_xor(nv3, 32);
        if (q == 0) {
            s_nv[col]       = nv0;
            s_nv[128 + col] = nv1;
            s_nv[256 + col] = nv2;
            s_nv[384 + col] = nv3;
        }
    }
    __syncthreads();                                   // bar5

    // ---- phase 7: node LN (waves 0-3 -> nodes 0-3) ----
    if (w < 4) {
        float v0 = s_nv[w * 128 + l], v1 = s_nv[w * 128 + 64 + l];
        float s = v0 + v1, qv = v0 * v0 + v1 * v1;
        #pragma unroll
        for (int d = 1; d < 64; d <<= 1) { s += __shfl_xor(s, d); qv += __shfl_xor(qv, d); }
        float mu2 = s * (1.f / 128.f);
        float rstd = rsqrtf(qv * (1.f / 128.f) - mu2 * mu2 + 1e-5f);
        size_t nb = ((size_t)(rb >> 5) + w) * 128;
        out_node[nb + l]      = (v0 - mu2) * rstd * g_node[l]      + b_node[l];
        out_node[nb + 64 + l] = (v1 - mu2) * rstd * g_node[64 + l] + b_node[64 + l];
    }
}

extern "C" void kernel_launch(void* const* d_in, const int* in_sizes, int n_in,
                              void* d_out, int out_size, void* d_ws, size_t ws_size,
                              hipStream_t stream) {
    const float* ef     = (const float*)d_in[0];
    const int*   mask   = (const int*)d_in[1];
    const float* Wlin   = (const float*)d_in[2];
    const float* b_lin  = (const float*)d_in[3];
    const float* g_edge = (const float*)d_in[4];
    const float* b_edge = (const float*)d_in[5];
    const float* W1     = (const float*)d_in[6];
    const float* b1     = (const float*)d_in[7];
    const float* W2     = (const float*)d_in[8];
    const float* b2     = (const float*)d_in[9];
    const float* g_node = (const float*)d_in[10];
    const float* b_node = (const float*)d_in[11];

    int N = in_sizes[0] / (32 * 256);

    unsigned short* wlinT = (unsigned short*)d_ws;          // [128][256] bf16
    unsigned short* w1gT  = wlinT + 128 * 256;              // [128][128] bf16 (g-folded)
    unsigned short* w2T   = w1gT + 128 * 128;               // [128][128] bf16
    float*          b1f   = (float*)(w2T + 128 * 128);      // [128] f32

    float* out_node = (float*)d_out;
    float* out_edge = out_node + (size_t)N * 128;

    prep1<<<128, 256, 0, stream>>>(Wlin, W2, wlinT, w2T);
    prep2<<<128, 128, 0, stream>>>(W1, g_edge, b_edge, b1, w1gT, b1f);
    int nblocks = (N * 32 + 127) / 128;                     // N=20000 -> 5000 exact
    fused_kernel<<<nblocks, 512, 0, stream>>>(ef, mask, wlinT, w1gT, w2T,
                                              b_lin, b1f, b2, g_node, b_node,
                                              out_node, out_edge);
}